// Round 1
// baseline (609.953 us; speedup 1.0000x reference)
//
#include <hip/hip_runtime.h>

#define NTOK 4096
#define DIM  1024
#define HID  2816
#define NE   8

typedef short  s8bf  __attribute__((ext_vector_type(8)));   // 8 bf16 in 4 VGPRs
typedef float  f32x4 __attribute__((ext_vector_type(4)));

__device__ __forceinline__ unsigned short f2bf(float f) {
    union { float f; unsigned u; } v; v.f = f;
    unsigned r = v.u + 0x7FFFu + ((v.u >> 16) & 1u);   // RNE
    return (unsigned short)(r >> 16);
}

__device__ __forceinline__ void gld16(const void* g, void* l) {
    __builtin_amdgcn_global_load_lds(
        (const __attribute__((address_space(1))) unsigned int*)g,
        (__attribute__((address_space(3))) unsigned int*)l, 16, 0, 0);
}

// ---------------- router: logits, softmax, top-2, bucket scatter, x->bf16 ----
__global__ __launch_bounds__(256) void router_kernel(
    const float* __restrict__ x, const float* __restrict__ rw,
    unsigned short* __restrict__ xb, float* __restrict__ probs_buf,
    int* __restrict__ counts, int* __restrict__ idx_buf,
    float* __restrict__ wgt_buf) {
    __shared__ int lcnt[NE];
    __shared__ int gb[NE];
    int t = threadIdx.x;
    if (t < NE) lcnt[t] = 0;
    __syncthreads();

    int g = t >> 4, lg = t & 15;
    int token = blockIdx.x * 16 + g;
    const float4* xr = (const float4*)(x + (size_t)token * DIM);
    const float4* rw4 = (const float4*)rw;

    float p[NE];
#pragma unroll
    for (int e = 0; e < NE; ++e) p[e] = 0.f;

#pragma unroll 4
    for (int j = 0; j < 16; ++j) {
        int idx = lg + 16 * j;           // float4 index within row
        float4 xv = xr[idx];
        ushort4 o;
        o.x = f2bf(xv.x); o.y = f2bf(xv.y); o.z = f2bf(xv.z); o.w = f2bf(xv.w);
        ((ushort4*)xb)[(size_t)token * 256 + idx] = o;
#pragma unroll
        for (int e = 0; e < NE; ++e) {
            float4 wv = rw4[e * 256 + idx];
            p[e] += xv.x * wv.x + xv.y * wv.y + xv.z * wv.z + xv.w * wv.w;
        }
    }
#pragma unroll
    for (int e = 0; e < NE; ++e) {
        p[e] += __shfl_xor(p[e], 1, 64);
        p[e] += __shfl_xor(p[e], 2, 64);
        p[e] += __shfl_xor(p[e], 4, 64);
        p[e] += __shfl_xor(p[e], 8, 64);
    }

    int e0 = 0, e1 = 1; float cw0 = 0.f, cw1 = 0.f;
    int lp0 = 0, lp1 = 0;
    if (lg == 0) {
        float m = p[0];
#pragma unroll
        for (int e = 1; e < NE; ++e) m = fmaxf(m, p[e]);
        float pr[NE], s = 0.f;
#pragma unroll
        for (int e = 0; e < NE; ++e) { pr[e] = expf(p[e] - m); s += pr[e]; }
        float inv = 1.f / s;
#pragma unroll
        for (int e = 0; e < NE; ++e) { pr[e] *= inv; probs_buf[token * NE + e] = pr[e]; }
        // top-2 (ties -> lower index, matches lax.top_k)
        e0 = 0;
#pragma unroll
        for (int e = 1; e < NE; ++e) if (pr[e] > pr[e0]) e0 = e;
        e1 = (e0 == 0) ? 1 : 0;
#pragma unroll
        for (int e = 0; e < NE; ++e) if (e != e0 && pr[e] > pr[e1]) e1 = e;
        float s2 = fmaxf(pr[e0] + pr[e1], 1e-9f);
        cw0 = pr[e0] / s2; cw1 = pr[e1] / s2;
        lp0 = atomicAdd(&lcnt[e0], 1);
        lp1 = atomicAdd(&lcnt[e1], 1);
    }
    __syncthreads();
    if (t < NE) gb[t] = atomicAdd(&counts[t], lcnt[t]);
    __syncthreads();
    if (lg == 0) {
        int q0 = gb[e0] + lp0, q1 = gb[e1] + lp1;
        idx_buf[e0 * NTOK + q0] = token; wgt_buf[e0 * NTOK + q0] = cw0;
        idx_buf[e1 * NTOK + q1] = token; wgt_buf[e1 * NTOK + q1] = cw1;
    }
}

// ---------------- prefix sum of 8 counts ------------------------------------
__global__ void offsets_kernel(const int* __restrict__ counts, int* __restrict__ offsets) {
    if (threadIdx.x == 0 && blockIdx.x == 0) {
        int r = 0;
        for (int e = 0; e < NE; ++e) { offsets[e] = r; r += counts[e]; }
    }
}

// ---------------- f32 -> bf16 weight conversion ------------------------------
__global__ __launch_bounds__(256) void cvt_kernel(const float4* __restrict__ s,
                                                  uint4* __restrict__ d, int n8) {
    int i = blockIdx.x * 256 + threadIdx.x;
    if (i >= n8) return;
    float4 a = s[2 * i], b = s[2 * i + 1];
    union { unsigned short u[8]; uint4 v; } o;
    o.u[0] = f2bf(a.x); o.u[1] = f2bf(a.y); o.u[2] = f2bf(a.z); o.u[3] = f2bf(a.w);
    o.u[4] = f2bf(b.x); o.u[5] = f2bf(b.y); o.u[6] = f2bf(b.z); o.u[7] = f2bf(b.w);
    d[i] = o.v;
}

// ---------------- GEMM1: h = silu(x@w1^T) * (x@w3^T), gathered rows ----------
// block: 128 tokens x 64 hidden units; B-tile rows 0..63 = w1, 64..127 = w3.
// 4 waves = 4 M-stripes of 32 rows, each wave computes both gate and up.
__global__ __launch_bounds__(256, 2) void gemm1_kernel(
    const unsigned short* __restrict__ xb,
    const unsigned short* __restrict__ w1b,
    const unsigned short* __restrict__ w3b,
    const int* __restrict__ counts, const int* __restrict__ offsets,
    const int* __restrict__ idx_buf,
    unsigned short* __restrict__ h) {
    int raw = blockIdx.x;
    int e = raw & 7;              // XCD-bijective: each XCD owns one expert
    int slot = raw >> 3;          // 0..1407  (44 n-tiles * 32 m-tiles)
    int n_t = slot >> 5;          // 0..43
    int m_t = slot & 31;          // 0..31
    int cnt = counts[e];
    int m0 = m_t * 128;
    if (m0 >= cnt) return;
    int off_e = offsets[e];
    int n0 = n_t * 64;

    __shared__ unsigned short As[128 * 32];
    __shared__ unsigned short Bs[128 * 32];

    int t = threadIdx.x;
    int arow = t >> 2; int c8 = (t & 3) * 8;
    int r0 = m0 + arow, r1 = r0 + 64;
    int tok0 = idx_buf[e * NTOK + (r0 < cnt ? r0 : cnt - 1)];
    int tok1 = idx_buf[e * NTOK + (r1 < cnt ? r1 : cnt - 1)];
    const unsigned short* pa0 = xb + (size_t)tok0 * DIM + c8;
    const unsigned short* pa1 = xb + (size_t)tok1 * DIM + c8;
    const unsigned short* pb0 = w1b + ((size_t)e * HID + n0 + arow) * DIM + c8;
    const unsigned short* pb1 = w3b + ((size_t)e * HID + n0 + arow) * DIM + c8;
    unsigned short* la0 = As + t * 8;
    unsigned short* la1 = As + 2048 + t * 8;
    unsigned short* lb0 = Bs + t * 8;
    unsigned short* lb1 = Bs + 2048 + t * 8;

    f32x4 acc[2][8];
#pragma unroll
    for (int m = 0; m < 2; ++m)
#pragma unroll
        for (int n = 0; n < 8; ++n) acc[m][n] = (f32x4){0.f, 0.f, 0.f, 0.f};

    int lane = t & 63, wid = t >> 6;
    int lr = lane & 15, lk = (lane >> 4) * 8;

    for (int kk = 0; kk < DIM; kk += 32) {
        __syncthreads();
        gld16(pa0, la0); gld16(pa1, la1); gld16(pb0, lb0); gld16(pb1, lb1);
        pa0 += 32; pa1 += 32; pb0 += 32; pb1 += 32;
        __syncthreads();
        s8bf a[2], b[8];
#pragma unroll
        for (int m = 0; m < 2; ++m)
            a[m] = *(const s8bf*)&As[(wid * 32 + m * 16 + lr) * 32 + lk];
#pragma unroll
        for (int n = 0; n < 8; ++n)
            b[n] = *(const s8bf*)&Bs[(n * 16 + lr) * 32 + lk];
#pragma unroll
        for (int m = 0; m < 2; ++m)
#pragma unroll
            for (int n = 0; n < 8; ++n)
                acc[m][n] = __builtin_amdgcn_mfma_f32_16x16x32_bf16(a[m], b[n], acc[m][n], 0, 0, 0);
    }

    int rq = (lane >> 4) * 4;
#pragma unroll
    for (int m = 0; m < 2; ++m)
#pragma unroll
        for (int n = 0; n < 4; ++n) {
            f32x4 g4 = acc[m][n], u4 = acc[m][n + 4];
#pragma unroll
            for (int r = 0; r < 4; ++r) {
                int row = m0 + wid * 32 + m * 16 + rq + r;
                if (row < cnt) {
                    float g = g4[r], u = u4[r];
                    float hv = (g / (1.f + __expf(-g))) * u;    // silu(g)*u
                    h[(size_t)(off_e + row) * HID + (n0 + n * 16 + lr)] = f2bf(hv);
                }
            }
        }
}

// ---------------- GEMM2: y = h @ w2^T, scaled combine via atomics ------------
__global__ __launch_bounds__(256, 2) void gemm2_kernel(
    const unsigned short* __restrict__ h,
    const unsigned short* __restrict__ w2b,
    const int* __restrict__ counts, const int* __restrict__ offsets,
    const int* __restrict__ idx_buf, const float* __restrict__ wgt_buf,
    float* __restrict__ out) {
    int raw = blockIdx.x;
    int e = raw & 7;
    int slot = raw >> 3;          // 0..255  (8 n-tiles * 32 m-tiles)
    int n_t = slot >> 5;          // 0..7
    int m_t = slot & 31;
    int cnt = counts[e];
    int m0 = m_t * 128;
    if (m0 >= cnt) return;
    int off_e = offsets[e];
    int n0 = n_t * 128;

    __shared__ unsigned short As[128 * 32];
    __shared__ unsigned short Bs[128 * 32];

    int t = threadIdx.x;
    int arow = t >> 2; int c8 = (t & 3) * 8;
    int r0 = m0 + arow, r1 = r0 + 64;
    int gr0 = off_e + (r0 < cnt ? r0 : cnt - 1);
    int gr1 = off_e + (r1 < cnt ? r1 : cnt - 1);
    const unsigned short* pa0 = h + (size_t)gr0 * HID + c8;
    const unsigned short* pa1 = h + (size_t)gr1 * HID + c8;
    const unsigned short* pb0 = w2b + ((size_t)e * DIM + n0 + arow) * HID + c8;
    const unsigned short* pb1 = w2b + ((size_t)e * DIM + n0 + 64 + arow) * HID + c8;
    unsigned short* la0 = As + t * 8;
    unsigned short* la1 = As + 2048 + t * 8;
    unsigned short* lb0 = Bs + t * 8;
    unsigned short* lb1 = Bs + 2048 + t * 8;

    f32x4 acc[4][4];
#pragma unroll
    for (int m = 0; m < 4; ++m)
#pragma unroll
        for (int n = 0; n < 4; ++n) acc[m][n] = (f32x4){0.f, 0.f, 0.f, 0.f};

    int lane = t & 63, wid = t >> 6;
    int wr = wid >> 1, wc = wid & 1;
    int lr = lane & 15, lk = (lane >> 4) * 8;

    for (int kk = 0; kk < HID; kk += 32) {
        __syncthreads();
        gld16(pa0, la0); gld16(pa1, la1); gld16(pb0, lb0); gld16(pb1, lb1);
        pa0 += 32; pa1 += 32; pb0 += 32; pb1 += 32;
        __syncthreads();
        s8bf a[4], b[4];
#pragma unroll
        for (int m = 0; m < 4; ++m)
            a[m] = *(const s8bf*)&As[(wr * 64 + m * 16 + lr) * 32 + lk];
#pragma unroll
        for (int n = 0; n < 4; ++n)
            b[n] = *(const s8bf*)&Bs[(wc * 64 + n * 16 + lr) * 32 + lk];
#pragma unroll
        for (int m = 0; m < 4; ++m)
#pragma unroll
            for (int n = 0; n < 4; ++n)
                acc[m][n] = __builtin_amdgcn_mfma_f32_16x16x32_bf16(a[m], b[n], acc[m][n], 0, 0, 0);
    }

    int rq = (lane >> 4) * 4;
#pragma unroll
    for (int m = 0; m < 4; ++m) {
#pragma unroll
        for (int r = 0; r < 4; ++r) {
            int row = m0 + wr * 64 + m * 16 + rq + r;
            if (row < cnt) {
                int si = e * NTOK + row;
                float wgt = wgt_buf[si];
                int tok = idx_buf[si];
                float* orow = out + (size_t)tok * DIM + n0 + wc * 64;
#pragma unroll
                for (int n = 0; n < 4; ++n)
                    atomicAdd(&orow[n * 16 + lr], wgt * acc[m][n][r]);
            }
        }
    }
}

// ---------------- aux loss ----------------------------------------------------
__global__ __launch_bounds__(256) void aux_kernel(const float* __restrict__ probs_buf,
                                                  float* __restrict__ out_aux) {
    __shared__ float sd[256 * 16];
    float acc[16];
#pragma unroll
    for (int j = 0; j < 16; ++j) acc[j] = 0.f;
    int t = threadIdx.x;
    for (int tok = t; tok < NTOK; tok += 256) {
#pragma unroll
        for (int e = 0; e < NE; ++e) {
            float p = probs_buf[tok * NE + e];
            acc[e] += p;
            acc[NE + e] += (p > 0.125f) ? 1.f : 0.f;
        }
    }
#pragma unroll
    for (int j = 0; j < 16; ++j) sd[t * 16 + j] = acc[j];
    __syncthreads();
    for (int s = 128; s > 0; s >>= 1) {
        if (t < s) {
#pragma unroll
            for (int j = 0; j < 16; ++j) sd[t * 16 + j] += sd[(t + s) * 16 + j];
        }
        __syncthreads();
    }
    if (t == 0) {
        float aux = 0.f;
        for (int e = 0; e < NE; ++e)
            aux += (sd[e] / (float)NTOK) * (sd[NE + e] / (float)NTOK);
        out_aux[0] = aux * (float)(NE * NE);
    }
}

extern "C" void kernel_launch(void* const* d_in, const int* in_sizes, int n_in,
                              void* d_out, int out_size, void* d_ws, size_t ws_size,
                              hipStream_t stream) {
    const float* x  = (const float*)d_in[0];
    const float* rw = (const float*)d_in[1];
    const float* w1 = (const float*)d_in[2];
    const float* w2 = (const float*)d_in[3];
    const float* w3 = (const float*)d_in[4];
    float* out = (float*)d_out;

    char* ws = (char*)d_ws;
    size_t o = 0;
    unsigned short* xb   = (unsigned short*)(ws + o); o += (size_t)NTOK * DIM * 2;
    unsigned short* w1b  = (unsigned short*)(ws + o); o += (size_t)NE * HID * DIM * 2;
    unsigned short* w3b  = (unsigned short*)(ws + o); o += (size_t)NE * HID * DIM * 2;
    unsigned short* w2b  = (unsigned short*)(ws + o); o += (size_t)NE * DIM * HID * 2;
    unsigned short* hbuf = (unsigned short*)(ws + o); o += (size_t)NTOK * 2 * HID * 2;
    int*   counts   = (int*)(ws + o);   o += 256;
    int*   offsets  = (int*)(ws + o);   o += 256;
    int*   idx_buf  = (int*)(ws + o);   o += (size_t)NE * NTOK * 4;
    float* wgt_buf  = (float*)(ws + o); o += (size_t)NE * NTOK * 4;
    float* probs_buf= (float*)(ws + o); o += (size_t)NTOK * NE * 4;

    hipMemsetAsync(counts, 0, 256, stream);
    hipMemsetAsync(d_out, 0, (size_t)out_size * sizeof(float), stream);

    int n8 = NE * HID * DIM / 8;   // 2,883,584 -> 11264 blocks exactly
    cvt_kernel<<<n8 / 256, 256, 0, stream>>>((const float4*)w1, (uint4*)w1b, n8);
    cvt_kernel<<<n8 / 256, 256, 0, stream>>>((const float4*)w3, (uint4*)w3b, n8);
    cvt_kernel<<<n8 / 256, 256, 0, stream>>>((const float4*)w2, (uint4*)w2b, n8);

    router_kernel<<<NTOK / 16, 256, 0, stream>>>(x, rw, xb, probs_buf, counts, idx_buf, wgt_buf);
    offsets_kernel<<<1, 64, 0, stream>>>(counts, offsets);

    gemm1_kernel<<<8 * 44 * 32, 256, 0, stream>>>(xb, w1b, w3b, counts, offsets, idx_buf, hbuf);
    gemm2_kernel<<<8 * 8 * 32, 256, 0, stream>>>(hbuf, w2b, counts, offsets, idx_buf, wgt_buf, out);

    aux_kernel<<<1, 256, 0, stream>>>(probs_buf, out + ((size_t)out_size - 1));
}

// Round 5
// 541.028 us; speedup vs baseline: 1.1274x; 1.1274x over previous
//
#include <hip/hip_runtime.h>

#define NTOK 4096
#define DIM  1024
#define HID  2816
#define NE   8
#define TLMAX 80

typedef short  s8bf  __attribute__((ext_vector_type(8)));   // 8 bf16 in 4 VGPRs
typedef float  f32x4 __attribute__((ext_vector_type(4)));

__device__ __forceinline__ unsigned short f2bf(float f) {
    union { float f; unsigned u; } v; v.f = f;
    unsigned r = v.u + 0x7FFFu + ((v.u >> 16) & 1u);   // RNE
    return (unsigned short)(r >> 16);
}

__device__ __forceinline__ void gld16(const void* g, void* l) {
    __builtin_amdgcn_global_load_lds(
        (const __attribute__((address_space(1))) unsigned int*)g,
        (__attribute__((address_space(3))) unsigned int*)l, 16, 0, 0);
}

// ---------------- router: logits, softmax, top-2, bucket scatter, x->bf16 ----
__global__ __launch_bounds__(256) void router_kernel(
    const float* __restrict__ x, const float* __restrict__ rw,
    unsigned short* __restrict__ xb, float* __restrict__ probs_buf,
    int* __restrict__ counts, int* __restrict__ idx_buf,
    float* __restrict__ wgt_buf, int* __restrict__ tok2eq) {
    __shared__ int lcnt[NE];
    __shared__ int gb[NE];
    int t = threadIdx.x;
    if (t < NE) lcnt[t] = 0;
    __syncthreads();

    int g = t >> 4, lg = t & 15;
    int token = blockIdx.x * 16 + g;
    const float4* xr = (const float4*)(x + (size_t)token * DIM);
    const float4* rw4 = (const float4*)rw;

    float p[NE];
#pragma unroll
    for (int e = 0; e < NE; ++e) p[e] = 0.f;

#pragma unroll 4
    for (int j = 0; j < 16; ++j) {
        int idx = lg + 16 * j;           // float4 index within row
        float4 xv = xr[idx];
        ushort4 o;
        o.x = f2bf(xv.x); o.y = f2bf(xv.y); o.z = f2bf(xv.z); o.w = f2bf(xv.w);
        ((ushort4*)xb)[(size_t)token * 256 + idx] = o;
#pragma unroll
        for (int e = 0; e < NE; ++e) {
            float4 wv = rw4[e * 256 + idx];
            p[e] += xv.x * wv.x + xv.y * wv.y + xv.z * wv.z + xv.w * wv.w;
        }
    }
#pragma unroll
    for (int e = 0; e < NE; ++e) {
        p[e] += __shfl_xor(p[e], 1, 64);
        p[e] += __shfl_xor(p[e], 2, 64);
        p[e] += __shfl_xor(p[e], 4, 64);
        p[e] += __shfl_xor(p[e], 8, 64);
    }

    int e0 = 0, e1 = 1; float cw0 = 0.f, cw1 = 0.f;
    int lp0 = 0, lp1 = 0;
    if (lg == 0) {
        float m = p[0];
#pragma unroll
        for (int e = 1; e < NE; ++e) m = fmaxf(m, p[e]);
        float pr[NE], s = 0.f;
#pragma unroll
        for (int e = 0; e < NE; ++e) { pr[e] = expf(p[e] - m); s += pr[e]; }
        float inv = 1.f / s;
#pragma unroll
        for (int e = 0; e < NE; ++e) { pr[e] *= inv; probs_buf[token * NE + e] = pr[e]; }
        // top-2 (ties -> lower index, matches lax.top_k)
        e0 = 0;
#pragma unroll
        for (int e = 1; e < NE; ++e) if (pr[e] > pr[e0]) e0 = e;
        e1 = (e0 == 0) ? 1 : 0;
#pragma unroll
        for (int e = 0; e < NE; ++e) if (e != e0 && pr[e] > pr[e1]) e1 = e;
        float s2 = fmaxf(pr[e0] + pr[e1], 1e-9f);
        cw0 = pr[e0] / s2; cw1 = pr[e1] / s2;
        lp0 = atomicAdd(&lcnt[e0], 1);
        lp1 = atomicAdd(&lcnt[e1], 1);
    }
    __syncthreads();
    if (t < NE) gb[t] = atomicAdd(&counts[t], lcnt[t]);
    __syncthreads();
    if (lg == 0) {
        int q0 = gb[e0] + lp0, q1 = gb[e1] + lp1;
        idx_buf[e0 * NTOK + q0] = token; wgt_buf[e0 * NTOK + q0] = cw0;
        idx_buf[e1 * NTOK + q1] = token; wgt_buf[e1 * NTOK + q1] = cw1;
        tok2eq[2 * token]     = (e0 << 12) | q0;
        tok2eq[2 * token + 1] = (e1 << 12) | q1;
    }
}

// ---------------- prefix sum + work-queue tile list ---------------------------
__global__ void offsets_kernel(const int* __restrict__ counts, int* __restrict__ offsets,
                               int* __restrict__ tiles) {
    if (threadIdx.x == 0 && blockIdx.x == 0) {
        int r = 0;
        for (int e = 0; e < NE; ++e) { offsets[e] = r; r += counts[e]; }
        int nt = 0;
        for (int e = 0; e < NE; ++e)
            for (int m0 = 0; m0 < counts[e]; m0 += 128)
                tiles[1 + nt++] = (e << 16) | (m0 >> 7);
        tiles[0] = nt;
    }
}

// ---------------- f32 -> bf16 conversion of w1,w3,w2 (fused) -----------------
__global__ __launch_bounds__(256) void cvt3_kernel(
    const float4* __restrict__ w1, const float4* __restrict__ w3,
    const float4* __restrict__ w2, uint4* __restrict__ d1,
    uint4* __restrict__ d3, uint4* __restrict__ d2, int n8) {
    int i = blockIdx.x * 256 + threadIdx.x;
    const float4* s; uint4* d;
    if (i < n8)            { s = w1; d = d1; }
    else if (i < 2 * n8)   { s = w3; d = d3; i -= n8; }
    else                   { s = w2; d = d2; i -= 2 * n8; }
    float4 a = s[2 * i], b = s[2 * i + 1];
    union { unsigned short u[8]; uint4 v; } o;
    o.u[0] = f2bf(a.x); o.u[1] = f2bf(a.y); o.u[2] = f2bf(a.z); o.u[3] = f2bf(a.w);
    o.u[4] = f2bf(b.x); o.u[5] = f2bf(b.y); o.u[6] = f2bf(b.z); o.u[7] = f2bf(b.w);
    d[i] = o.v;
}

// ---------------- GEMM1: h = silu(x@w1^T) * (x@w3^T), gathered rows ----------
// tile: 128 tokens x 64 hid; B-tile 128 rows = 64 w1-rows + 64 w3-rows.
// BK=64, LDS XOR-swizzled (rule #21: linear gld16 dest + pre-swizzled global
// source column + swizzled ds_read).
__global__ __launch_bounds__(256, 3) void gemm1_kernel(
    const unsigned short* __restrict__ xb,
    const unsigned short* __restrict__ w1b,
    const unsigned short* __restrict__ w3b,
    const int* __restrict__ counts, const int* __restrict__ offsets,
    const int* __restrict__ idx_buf, const int* __restrict__ tiles,
    unsigned short* __restrict__ h) {
    int nt = tiles[0];
    int tile_id = blockIdx.x % TLMAX;
    int n_t = blockIdx.x / TLMAX;          // 0..43
    if (tile_id >= nt) return;
    int tv = tiles[1 + tile_id];
    int e = tv >> 16;
    int m0 = (tv & 0xffff) << 7;
    int cnt = counts[e];
    int off_e = offsets[e];
    int n0 = n_t * 64;

    __shared__ unsigned short As[128 * 64];   // 16 KB
    __shared__ unsigned short Bs[128 * 64];   // 16 KB

    int t = threadIdx.x;
    int s = t & 7, sub = t >> 3;              // slot (16B units), subrow
    const unsigned short* paA[4];
    const unsigned short* pbB[4];
#pragma unroll
    for (int p = 0; p < 4; ++p) {
        int row = p * 32 + sub;               // 0..127
        int rr = m0 + row;
        int tok = idx_buf[e * NTOK + (rr < cnt ? rr : cnt - 1)];
        paA[p] = xb + (size_t)tok * DIM + ((s ^ (row & 7)) * 8);
        int hr = n0 + (row & 63);
        const unsigned short* base = (row < 64) ? w1b : w3b;
        pbB[p] = base + ((size_t)e * HID + hr) * DIM + ((s ^ (row & 7)) * 8);
    }

    f32x4 acc[2][8];
#pragma unroll
    for (int m = 0; m < 2; ++m)
#pragma unroll
        for (int n = 0; n < 8; ++n) acc[m][n] = (f32x4){0.f, 0.f, 0.f, 0.f};

    int lane = t & 63, wid = t >> 6;
    int lr = lane & 15, hi = lane >> 4;       // hi 0..3
    int swz = (lr & 7) << 4;
    const char* Ab = (const char*)As;
    const char* Bb = (const char*)Bs;
    int arow0 = (wid * 32 + lr) * 128;
    int arow1 = (wid * 32 + 16 + lr) * 128;

    for (int kk = 0; kk < DIM; kk += 64) {
        __syncthreads();
#pragma unroll
        for (int p = 0; p < 4; ++p) gld16(paA[p] + kk, As + p * 2048 + t * 8);
#pragma unroll
        for (int p = 0; p < 4; ++p) gld16(pbB[p] + kk, Bs + p * 2048 + t * 8);
        __syncthreads();
#pragma unroll
        for (int ks = 0; ks < 2; ++ks) {
            int koff = (ks * 64 + hi * 16) ^ swz;
            s8bf a[2], b[8];
            a[0] = *(const s8bf*)(Ab + arow0 + koff);
            a[1] = *(const s8bf*)(Ab + arow1 + koff);
#pragma unroll
            for (int n = 0; n < 8; ++n)
                b[n] = *(const s8bf*)(Bb + (n * 16 + lr) * 128 + koff);
#pragma unroll
            for (int m = 0; m < 2; ++m)
#pragma unroll
                for (int n = 0; n < 8; ++n)
                    acc[m][n] = __builtin_amdgcn_mfma_f32_16x16x32_bf16(a[m], b[n], acc[m][n], 0, 0, 0);
        }
    }

    int rq = hi * 4;
#pragma unroll
    for (int m = 0; m < 2; ++m)
#pragma unroll
        for (int n = 0; n < 4; ++n) {
            f32x4 g4 = acc[m][n], u4 = acc[m][n + 4];
#pragma unroll
            for (int r = 0; r < 4; ++r) {
                int row = m0 + wid * 32 + m * 16 + rq + r;
                if (row < cnt) {
                    float gg = g4[r], u = u4[r];
                    float hv = (gg / (1.f + __expf(-gg))) * u;    // silu(g)*u
                    h[(size_t)(off_e + row) * HID + (n0 + n * 16 + lr)] = f2bf(hv);
                }
            }
        }
}

// ---------------- GEMM2: y[gslot] = wgt * (h @ w2^T)  (no atomics) -----------
__global__ __launch_bounds__(256, 3) void gemm2_kernel(
    const unsigned short* __restrict__ h,
    const unsigned short* __restrict__ w2b,
    const int* __restrict__ counts, const int* __restrict__ offsets,
    const float* __restrict__ wgt_buf, const int* __restrict__ tiles,
    float* __restrict__ y) {
    int nt = tiles[0];
    int tile_id = blockIdx.x % TLMAX;
    int n_t = blockIdx.x / TLMAX;          // 0..7
    if (tile_id >= nt) return;
    int tv = tiles[1 + tile_id];
    int e = tv >> 16;
    int m0 = (tv & 0xffff) << 7;
    int cnt = counts[e];
    int off_e = offsets[e];
    int n0 = n_t * 128;

    __shared__ unsigned short As[128 * 64];
    __shared__ unsigned short Bs[128 * 64];

    int t = threadIdx.x;
    int s = t & 7, sub = t >> 3;
    const unsigned short* paA[4];
    const unsigned short* pbB[4];
#pragma unroll
    for (int p = 0; p < 4; ++p) {
        int row = p * 32 + sub;
        int rr = m0 + row;
        int grow = off_e + (rr < cnt ? rr : cnt - 1);
        paA[p] = h + (size_t)grow * HID + ((s ^ (row & 7)) * 8);
        pbB[p] = w2b + ((size_t)e * DIM + n0 + row) * HID + ((s ^ (row & 7)) * 8);
    }

    f32x4 acc[4][4];
#pragma unroll
    for (int m = 0; m < 4; ++m)
#pragma unroll
        for (int n = 0; n < 4; ++n) acc[m][n] = (f32x4){0.f, 0.f, 0.f, 0.f};

    int lane = t & 63, wid = t >> 6;
    int wr = wid >> 1, wc = wid & 1;
    int lr = lane & 15, hi = lane >> 4;
    int swz = (lr & 7) << 4;
    const char* Ab = (const char*)As;
    const char* Bb = (const char*)Bs;

    for (int kk = 0; kk < HID; kk += 64) {
        __syncthreads();
#pragma unroll
        for (int p = 0; p < 4; ++p) gld16(paA[p] + kk, As + p * 2048 + t * 8);
#pragma unroll
        for (int p = 0; p < 4; ++p) gld16(pbB[p] + kk, Bs + p * 2048 + t * 8);
        __syncthreads();
#pragma unroll
        for (int ks = 0; ks < 2; ++ks) {
            int koff = (ks * 64 + hi * 16) ^ swz;
            s8bf a[4], b[4];
#pragma unroll
            for (int m = 0; m < 4; ++m)
                a[m] = *(const s8bf*)(Ab + (wr * 64 + m * 16 + lr) * 128 + koff);
#pragma unroll
            for (int n = 0; n < 4; ++n)
                b[n] = *(const s8bf*)(Bb + (wc * 64 + n * 16 + lr) * 128 + koff);
#pragma unroll
            for (int m = 0; m < 4; ++m)
#pragma unroll
                for (int n = 0; n < 4; ++n)
                    acc[m][n] = __builtin_amdgcn_mfma_f32_16x16x32_bf16(a[m], b[n], acc[m][n], 0, 0, 0);
        }
    }

    int rq = hi * 4;
#pragma unroll
    for (int m = 0; m < 4; ++m) {
#pragma unroll
        for (int r = 0; r < 4; ++r) {
            int row = m0 + wr * 64 + m * 16 + rq + r;
            if (row < cnt) {
                float wgt = wgt_buf[e * NTOK + row];
                float* yrow = y + (size_t)(off_e + row) * DIM + n0 + wc * 64;
#pragma unroll
                for (int n = 0; n < 4; ++n)
                    yrow[n * 16 + lr] = wgt * acc[m][n][r];
            }
        }
    }
}

// ---------------- combine: out[tok] = y[slot0] + y[slot1] --------------------
__global__ __launch_bounds__(256) void combine_kernel(
    const float4* __restrict__ y, const int* __restrict__ tok2eq,
    const int* __restrict__ offsets, float4* __restrict__ out) {
    int tok = blockIdx.x;
    int v0 = tok2eq[2 * tok], v1 = tok2eq[2 * tok + 1];
    int g0 = offsets[v0 >> 12] + (v0 & 4095);
    int g1 = offsets[v1 >> 12] + (v1 & 4095);
    int t = threadIdx.x;
    out[(size_t)tok * 256 + t] = y[(size_t)g0 * 256 + t] + y[(size_t)g1 * 256 + t];
}

// ---------------- aux loss ----------------------------------------------------
__global__ __launch_bounds__(256) void aux_kernel(const float* __restrict__ probs_buf,
                                                  float* __restrict__ out_aux) {
    __shared__ float sd[256 * 16];
    float acc[16];
#pragma unroll
    for (int j = 0; j < 16; ++j) acc[j] = 0.f;
    int t = threadIdx.x;
    for (int tok = t; tok < NTOK; tok += 256) {
#pragma unroll
        for (int e = 0; e < NE; ++e) {
            float p = probs_buf[tok * NE + e];
            acc[e] += p;
            acc[NE + e] += (p > 0.125f) ? 1.f : 0.f;
        }
    }
#pragma unroll
    for (int j = 0; j < 16; ++j) sd[t * 16 + j] = acc[j];
    __syncthreads();
    for (int ss = 128; ss > 0; ss >>= 1) {
        if (t < ss) {
#pragma unroll
            for (int j = 0; j < 16; ++j) sd[t * 16 + j] += sd[(t + ss) * 16 + j];
        }
        __syncthreads();
    }
    if (t == 0) {
        float aux = 0.f;
        for (int e = 0; e < NE; ++e)
            aux += (sd[e] / (float)NTOK) * (sd[NE + e] / (float)NTOK);
        out_aux[0] = aux * (float)(NE * NE);
    }
}

extern "C" void kernel_launch(void* const* d_in, const int* in_sizes, int n_in,
                              void* d_out, int out_size, void* d_ws, size_t ws_size,
                              hipStream_t stream) {
    const float* x  = (const float*)d_in[0];
    const float* rw = (const float*)d_in[1];
    const float* w1 = (const float*)d_in[2];
    const float* w2 = (const float*)d_in[3];
    const float* w3 = (const float*)d_in[4];
    float* out = (float*)d_out;

    char* ws = (char*)d_ws;
    size_t o = 0;
    unsigned short* xb   = (unsigned short*)(ws + o); o += (size_t)NTOK * DIM * 2;
    unsigned short* w1b  = (unsigned short*)(ws + o); o += (size_t)NE * HID * DIM * 2;
    unsigned short* w3b  = (unsigned short*)(ws + o); o += (size_t)NE * HID * DIM * 2;
    unsigned short* w2b  = (unsigned short*)(ws + o); o += (size_t)NE * DIM * HID * 2;
    unsigned short* hbuf = (unsigned short*)(ws + o); o += (size_t)NTOK * 2 * HID * 2;
    int*   counts   = (int*)(ws + o);   o += 256;
    int*   offsets  = (int*)(ws + o);   o += 256;
    int*   tiles    = (int*)(ws + o);   o += (TLMAX + 1) * 4 + 60;
    int*   idx_buf  = (int*)(ws + o);   o += (size_t)NE * NTOK * 4;
    float* wgt_buf  = (float*)(ws + o); o += (size_t)NE * NTOK * 4;
    float* probs_buf= (float*)(ws + o); o += (size_t)NTOK * NE * 4;
    int*   tok2eq   = (int*)(ws + o);   o += (size_t)NTOK * 2 * 4;
    // y-buffer aliases w1b (dead after gemm1; rewritten by cvt3 every launch)
    float* ybuf = (float*)w1b;          // NTOK*2*DIM f32 = 33.5 MB <= 46.1 MB

    hipMemsetAsync(counts, 0, 256, stream);

    int n8 = NE * HID * DIM / 8;        // 2,883,584
    cvt3_kernel<<<3 * n8 / 256, 256, 0, stream>>>(
        (const float4*)w1, (const float4*)w3, (const float4*)w2,
        (uint4*)w1b, (uint4*)w3b, (uint4*)w2b, n8);

    router_kernel<<<NTOK / 16, 256, 0, stream>>>(x, rw, xb, probs_buf, counts,
                                                 idx_buf, wgt_buf, tok2eq);
    offsets_kernel<<<1, 64, 0, stream>>>(counts, offsets, tiles);

    gemm1_kernel<<<(HID / 64) * TLMAX, 256, 0, stream>>>(
        xb, w1b, w3b, counts, offsets, idx_buf, tiles, hbuf);
    gemm2_kernel<<<(DIM / 128) * TLMAX, 256, 0, stream>>>(
        hbuf, w2b, counts, offsets, wgt_buf, tiles, ybuf);

    combine_kernel<<<NTOK, 256, 0, stream>>>((const float4*)ybuf, tok2eq, offsets,
                                             (float4*)out);
    aux_kernel<<<1, 256, 0, stream>>>(probs_buf, out + ((size_t)out_size - 1));
}

// Round 6
// 511.720 us; speedup vs baseline: 1.1920x; 1.0573x over previous
//
#include <hip/hip_runtime.h>

#define NTOK 4096
#define DIM  1024
#define HID  2816
#define NE   8
#define TLMAX 80

typedef short  s8bf  __attribute__((ext_vector_type(8)));   // 8 bf16 in 4 VGPRs
typedef float  f32x4 __attribute__((ext_vector_type(4)));

__device__ __forceinline__ unsigned short f2bf(float f) {
    union { float f; unsigned u; } v; v.f = f;
    unsigned r = v.u + 0x7FFFu + ((v.u >> 16) & 1u);   // RNE
    return (unsigned short)(r >> 16);
}

// pack 2 f32 -> 2 bf16 (truncation; |rel err| <= 2^-8, fine vs 0.52 threshold)
__device__ __forceinline__ unsigned pk2(float lo, float hi) {
    union { float f; unsigned u; } a, b; a.f = lo; b.f = hi;
    return (b.u & 0xFFFF0000u) | (a.u >> 16);
}

__device__ __forceinline__ void gld16(const void* g, void* l) {
    __builtin_amdgcn_global_load_lds(
        (const __attribute__((address_space(1))) unsigned int*)g,
        (__attribute__((address_space(3))) unsigned int*)l, 16, 0, 0);
}

// ---------------- router: logits, softmax, top-2, bucket scatter, x->bf16 ----
__global__ __launch_bounds__(256) void router_kernel(
    const float* __restrict__ x, const float* __restrict__ rw,
    unsigned short* __restrict__ xb, float* __restrict__ probs_buf,
    int* __restrict__ counts, int* __restrict__ idx_buf,
    float* __restrict__ wgt_buf, int* __restrict__ tok2eq) {
    __shared__ int lcnt[NE];
    __shared__ int gb[NE];
    int t = threadIdx.x;
    if (t < NE) lcnt[t] = 0;
    __syncthreads();

    int g = t >> 4, lg = t & 15;
    int token = blockIdx.x * 16 + g;
    const float4* xr = (const float4*)(x + (size_t)token * DIM);
    const float4* rw4 = (const float4*)rw;

    float p[NE];
#pragma unroll
    for (int e = 0; e < NE; ++e) p[e] = 0.f;

#pragma unroll 4
    for (int j = 0; j < 16; ++j) {
        int idx = lg + 16 * j;           // float4 index within row
        float4 xv = xr[idx];
        ushort4 o;
        o.x = f2bf(xv.x); o.y = f2bf(xv.y); o.z = f2bf(xv.z); o.w = f2bf(xv.w);
        ((ushort4*)xb)[(size_t)token * 256 + idx] = o;
#pragma unroll
        for (int e = 0; e < NE; ++e) {
            float4 wv = rw4[e * 256 + idx];
            p[e] += xv.x * wv.x + xv.y * wv.y + xv.z * wv.z + xv.w * wv.w;
        }
    }
#pragma unroll
    for (int e = 0; e < NE; ++e) {
        p[e] += __shfl_xor(p[e], 1, 64);
        p[e] += __shfl_xor(p[e], 2, 64);
        p[e] += __shfl_xor(p[e], 4, 64);
        p[e] += __shfl_xor(p[e], 8, 64);
    }

    int e0 = 0, e1 = 1; float cw0 = 0.f, cw1 = 0.f;
    int lp0 = 0, lp1 = 0;
    if (lg == 0) {
        float m = p[0];
#pragma unroll
        for (int e = 1; e < NE; ++e) m = fmaxf(m, p[e]);
        float pr[NE], s = 0.f;
#pragma unroll
        for (int e = 0; e < NE; ++e) { pr[e] = expf(p[e] - m); s += pr[e]; }
        float inv = 1.f / s;
#pragma unroll
        for (int e = 0; e < NE; ++e) { pr[e] *= inv; probs_buf[token * NE + e] = pr[e]; }
        // top-2 (ties -> lower index, matches lax.top_k)
        e0 = 0;
#pragma unroll
        for (int e = 1; e < NE; ++e) if (pr[e] > pr[e0]) e0 = e;
        e1 = (e0 == 0) ? 1 : 0;
#pragma unroll
        for (int e = 0; e < NE; ++e) if (e != e0 && pr[e] > pr[e1]) e1 = e;
        float s2 = fmaxf(pr[e0] + pr[e1], 1e-9f);
        cw0 = pr[e0] / s2; cw1 = pr[e1] / s2;
        lp0 = atomicAdd(&lcnt[e0], 1);
        lp1 = atomicAdd(&lcnt[e1], 1);
    }
    __syncthreads();
    if (t < NE) gb[t] = atomicAdd(&counts[t], lcnt[t]);
    __syncthreads();
    if (lg == 0) {
        int q0 = gb[e0] + lp0, q1 = gb[e1] + lp1;
        idx_buf[e0 * NTOK + q0] = token; wgt_buf[e0 * NTOK + q0] = cw0;
        idx_buf[e1 * NTOK + q1] = token; wgt_buf[e1 * NTOK + q1] = cw1;
        tok2eq[2 * token]     = (e0 << 12) | q0;
        tok2eq[2 * token + 1] = (e1 << 12) | q1;
    }
}

// ------- prefix sum + XCD-aligned round-robin tile list (expert = idx%8) ------
__global__ void offsets_kernel(const int* __restrict__ counts, int* __restrict__ offsets,
                               int* __restrict__ tiles) {
    if (threadIdx.x == 0 && blockIdx.x == 0) {
        int r = 0;
        int nt_e[NE]; int maxmt = 0, tot = 0;
        for (int e = 0; e < NE; ++e) {
            offsets[e] = r; r += counts[e];
            nt_e[e] = (counts[e] + 127) >> 7;
            tot += nt_e[e];
            if (nt_e[e] > maxmt) maxmt = nt_e[e];
        }
        if (8 * maxmt <= TLMAX) {
            // aligned mode: tile index mod 8 == expert  (XCD pinning)
            for (int m = 0; m < maxmt; ++m)
                for (int e = 0; e < NE; ++e)
                    tiles[1 + m * 8 + e] = (m < nt_e[e]) ? ((e << 16) | m) : -1;
            tiles[0] = 8 * maxmt;
        } else {
            // fallback: compact (correctness only; tot <= 71 always)
            int idx = 0;
            for (int e = 0; e < NE; ++e)
                for (int m = 0; m < nt_e[e]; ++m)
                    tiles[1 + idx++] = (e << 16) | m;
            tiles[0] = tot;
        }
    }
}

// ---------------- GEMM1: h = silu(x@w1^T) * (x@w3^T), gathered rows ----------
// tile: 128 tokens x 64 hid; B-tile 128 rows = 64 w1-rows + 64 w3-rows.
// A: bf16 gld16 with pre-swizzled source. B: f32 reg-staged, truncate-packed
// to bf16, ds_write to swizzled slot. LDS invariant both panels:
//   LDS[row][sigma] = src[row][sigma ^ (row&7)]   (16B slots)
__global__ __launch_bounds__(256, 3) void gemm1_kernel(
    const unsigned short* __restrict__ xb,
    const float* __restrict__ w1f,
    const float* __restrict__ w3f,
    const int* __restrict__ counts, const int* __restrict__ offsets,
    const int* __restrict__ idx_buf, const int* __restrict__ tiles,
    unsigned short* __restrict__ h) {
    int nt = tiles[0];
    int tile_id = blockIdx.x % TLMAX;
    int n_t = blockIdx.x / TLMAX;          // 0..43
    if (tile_id >= nt) return;
    int tv = tiles[1 + tile_id];
    if (tv < 0) return;
    int e = tv >> 16;
    int m0 = (tv & 0xffff) << 7;
    int cnt = counts[e];
    int off_e = offsets[e];
    int n0 = n_t * 64;

    __shared__ unsigned short As[128 * 64];   // 16 KB
    __shared__ unsigned short Bs[128 * 64];   // 16 KB

    int t = threadIdx.x;
    int s = t & 7, sub = t >> 3;              // slot (16B units), subrow
    const unsigned short* paA[4];
    const float* pbF[4];
    uint4* bdst[4];
#pragma unroll
    for (int p = 0; p < 4; ++p) {
        int row = p * 32 + sub;               // 0..127
        int rr = m0 + row;
        int tok = idx_buf[e * NTOK + (rr < cnt ? rr : cnt - 1)];
        paA[p] = xb + (size_t)tok * DIM + ((s ^ (row & 7)) * 8);
        int hr = n0 + (row & 63);
        const float* base = (row < 64) ? w1f : w3f;
        pbF[p] = base + ((size_t)e * HID + hr) * DIM + s * 8;
        bdst[p] = (uint4*)((char*)Bs + row * 128 + ((s ^ (row & 7)) * 16));
    }

    f32x4 acc[2][8];
#pragma unroll
    for (int m = 0; m < 2; ++m)
#pragma unroll
        for (int n = 0; n < 8; ++n) acc[m][n] = (f32x4){0.f, 0.f, 0.f, 0.f};

    int lane = t & 63, wid = t >> 6;
    int lr = lane & 15, hi = lane >> 4;       // hi 0..3
    int swz = (lr & 7) << 4;
    const char* Ab = (const char*)As;
    const char* Bb = (const char*)Bs;
    int arow0 = (wid * 32 + lr) * 128;
    int arow1 = (wid * 32 + 16 + lr) * 128;

    for (int kk = 0; kk < DIM; kk += 64) {
        __syncthreads();
#pragma unroll
        for (int p = 0; p < 4; ++p) gld16(paA[p] + kk, As + p * 2048 + t * 8);
#pragma unroll
        for (int p = 0; p < 4; ++p) {
            const float4* q = (const float4*)(pbF[p] + kk);
            float4 u = q[0], v = q[1];
            uint4 w;
            w.x = pk2(u.x, u.y); w.y = pk2(u.z, u.w);
            w.z = pk2(v.x, v.y); w.w = pk2(v.z, v.w);
            *bdst[p] = w;
        }
        __syncthreads();
#pragma unroll
        for (int ks = 0; ks < 2; ++ks) {
            int koff = (ks * 64 + hi * 16) ^ swz;
            s8bf a[2], b[8];
            a[0] = *(const s8bf*)(Ab + arow0 + koff);
            a[1] = *(const s8bf*)(Ab + arow1 + koff);
#pragma unroll
            for (int n = 0; n < 8; ++n)
                b[n] = *(const s8bf*)(Bb + (n * 16 + lr) * 128 + koff);
#pragma unroll
            for (int m = 0; m < 2; ++m)
#pragma unroll
                for (int n = 0; n < 8; ++n)
                    acc[m][n] = __builtin_amdgcn_mfma_f32_16x16x32_bf16(a[m], b[n], acc[m][n], 0, 0, 0);
        }
    }

    int rq = hi * 4;
#pragma unroll
    for (int m = 0; m < 2; ++m)
#pragma unroll
        for (int n = 0; n < 4; ++n) {
            f32x4 g4 = acc[m][n], u4 = acc[m][n + 4];
#pragma unroll
            for (int r = 0; r < 4; ++r) {
                int row = m0 + wid * 32 + m * 16 + rq + r;
                if (row < cnt) {
                    float gg = g4[r], u = u4[r];
                    float hv = (gg / (1.f + __expf(-gg))) * u;    // silu(g)*u
                    h[(size_t)(off_e + row) * HID + (n0 + n * 16 + lr)] = f2bf(hv);
                }
            }
        }
}

// ---------------- GEMM2: y[gslot] = wgt * (h @ w2^T)  (no atomics) -----------
__global__ __launch_bounds__(256, 3) void gemm2_kernel(
    const unsigned short* __restrict__ h,
    const float* __restrict__ w2f,
    const int* __restrict__ counts, const int* __restrict__ offsets,
    const float* __restrict__ wgt_buf, const int* __restrict__ tiles,
    float* __restrict__ y) {
    int nt = tiles[0];
    int tile_id = blockIdx.x % TLMAX;
    int n_t = blockIdx.x / TLMAX;          // 0..7
    if (tile_id >= nt) return;
    int tv = tiles[1 + tile_id];
    if (tv < 0) return;
    int e = tv >> 16;
    int m0 = (tv & 0xffff) << 7;
    int cnt = counts[e];
    int off_e = offsets[e];
    int n0 = n_t * 128;

    __shared__ unsigned short As[128 * 64];
    __shared__ unsigned short Bs[128 * 64];

    int t = threadIdx.x;
    int s = t & 7, sub = t >> 3;
    const unsigned short* paA[4];
    const float* pbF[4];
    uint4* bdst[4];
#pragma unroll
    for (int p = 0; p < 4; ++p) {
        int row = p * 32 + sub;
        int rr = m0 + row;
        int grow = off_e + (rr < cnt ? rr : cnt - 1);
        paA[p] = h + (size_t)grow * HID + ((s ^ (row & 7)) * 8);
        pbF[p] = w2f + ((size_t)e * DIM + n0 + row) * HID + s * 8;
        bdst[p] = (uint4*)((char*)Bs + row * 128 + ((s ^ (row & 7)) * 16));
    }

    f32x4 acc[4][4];
#pragma unroll
    for (int m = 0; m < 4; ++m)
#pragma unroll
        for (int n = 0; n < 4; ++n) acc[m][n] = (f32x4){0.f, 0.f, 0.f, 0.f};

    int lane = t & 63, wid = t >> 6;
    int wr = wid >> 1, wc = wid & 1;
    int lr = lane & 15, hi = lane >> 4;
    int swz = (lr & 7) << 4;
    const char* Ab = (const char*)As;
    const char* Bb = (const char*)Bs;

    for (int kk = 0; kk < HID; kk += 64) {
        __syncthreads();
#pragma unroll
        for (int p = 0; p < 4; ++p) gld16(paA[p] + kk, As + p * 2048 + t * 8);
#pragma unroll
        for (int p = 0; p < 4; ++p) {
            const float4* q = (const float4*)(pbF[p] + kk);
            float4 u = q[0], v = q[1];
            uint4 w;
            w.x = pk2(u.x, u.y); w.y = pk2(u.z, u.w);
            w.z = pk2(v.x, v.y); w.w = pk2(v.z, v.w);
            *bdst[p] = w;
        }
        __syncthreads();
#pragma unroll
        for (int ks = 0; ks < 2; ++ks) {
            int koff = (ks * 64 + hi * 16) ^ swz;
            s8bf a[4], b[4];
#pragma unroll
            for (int m = 0; m < 4; ++m)
                a[m] = *(const s8bf*)(Ab + (wr * 64 + m * 16 + lr) * 128 + koff);
#pragma unroll
            for (int n = 0; n < 4; ++n)
                b[n] = *(const s8bf*)(Bb + (wc * 64 + n * 16 + lr) * 128 + koff);
#pragma unroll
            for (int m = 0; m < 4; ++m)
#pragma unroll
                for (int n = 0; n < 4; ++n)
                    acc[m][n] = __builtin_amdgcn_mfma_f32_16x16x32_bf16(a[m], b[n], acc[m][n], 0, 0, 0);
        }
    }

    int rq = hi * 4;
#pragma unroll
    for (int m = 0; m < 4; ++m) {
#pragma unroll
        for (int r = 0; r < 4; ++r) {
            int row = m0 + wr * 64 + m * 16 + rq + r;
            if (row < cnt) {
                float wgt = wgt_buf[e * NTOK + row];
                float* yrow = y + (size_t)(off_e + row) * DIM + n0 + wc * 64;
#pragma unroll
                for (int n = 0; n < 4; ++n)
                    yrow[n * 16 + lr] = wgt * acc[m][n][r];
            }
        }
    }
}

// ---------------- combine: out[tok] = y[slot0] + y[slot1] --------------------
__global__ __launch_bounds__(256) void combine_kernel(
    const float4* __restrict__ y, const int* __restrict__ tok2eq,
    const int* __restrict__ offsets, float4* __restrict__ out) {
    int tok = blockIdx.x;
    int v0 = tok2eq[2 * tok], v1 = tok2eq[2 * tok + 1];
    int g0 = offsets[v0 >> 12] + (v0 & 4095);
    int g1 = offsets[v1 >> 12] + (v1 & 4095);
    int t = threadIdx.x;
    out[(size_t)tok * 256 + t] = y[(size_t)g0 * 256 + t] + y[(size_t)g1 * 256 + t];
}

// ---------------- aux loss ----------------------------------------------------
__global__ __launch_bounds__(256) void aux_kernel(const float* __restrict__ probs_buf,
                                                  float* __restrict__ out_aux) {
    __shared__ float sd[256 * 16];
    float acc[16];
#pragma unroll
    for (int j = 0; j < 16; ++j) acc[j] = 0.f;
    int t = threadIdx.x;
    for (int tok = t; tok < NTOK; tok += 256) {
#pragma unroll
        for (int e = 0; e < NE; ++e) {
            float p = probs_buf[tok * NE + e];
            acc[e] += p;
            acc[NE + e] += (p > 0.125f) ? 1.f : 0.f;
        }
    }
#pragma unroll
    for (int j = 0; j < 16; ++j) sd[t * 16 + j] = acc[j];
    __syncthreads();
    for (int ss = 128; ss > 0; ss >>= 1) {
        if (t < ss) {
#pragma unroll
            for (int j = 0; j < 16; ++j) sd[t * 16 + j] += sd[(t + ss) * 16 + j];
        }
        __syncthreads();
    }
    if (t == 0) {
        float aux = 0.f;
        for (int e = 0; e < NE; ++e)
            aux += (sd[e] / (float)NTOK) * (sd[NE + e] / (float)NTOK);
        out_aux[0] = aux * (float)(NE * NE);
    }
}

extern "C" void kernel_launch(void* const* d_in, const int* in_sizes, int n_in,
                              void* d_out, int out_size, void* d_ws, size_t ws_size,
                              hipStream_t stream) {
    const float* x  = (const float*)d_in[0];
    const float* rw = (const float*)d_in[1];
    const float* w1 = (const float*)d_in[2];
    const float* w2 = (const float*)d_in[3];
    const float* w3 = (const float*)d_in[4];
    float* out = (float*)d_out;

    char* ws = (char*)d_ws;
    size_t o = 0;
    unsigned short* xb   = (unsigned short*)(ws + o); o += (size_t)NTOK * DIM * 2;
    unsigned short* hbuf = (unsigned short*)(ws + o); o += (size_t)NTOK * 2 * HID * 2;
    float* ybuf          = (float*)(ws + o);          o += (size_t)NTOK * 2 * DIM * 4;
    int*   counts   = (int*)(ws + o);   o += 256;
    int*   offsets  = (int*)(ws + o);   o += 256;
    int*   tiles    = (int*)(ws + o);   o += (TLMAX + 1) * 4 + 60;
    int*   idx_buf  = (int*)(ws + o);   o += (size_t)NE * NTOK * 4;
    float* wgt_buf  = (float*)(ws + o); o += (size_t)NE * NTOK * 4;
    float* probs_buf= (float*)(ws + o); o += (size_t)NTOK * NE * 4;
    int*   tok2eq   = (int*)(ws + o);   o += (size_t)NTOK * 2 * 4;

    hipMemsetAsync(counts, 0, 256, stream);

    router_kernel<<<NTOK / 16, 256, 0, stream>>>(x, rw, xb, probs_buf, counts,
                                                 idx_buf, wgt_buf, tok2eq);
    offsets_kernel<<<1, 64, 0, stream>>>(counts, offsets, tiles);

    gemm1_kernel<<<(HID / 64) * TLMAX, 256, 0, stream>>>(
        xb, w1, w3, counts, offsets, idx_buf, tiles, hbuf);
    gemm2_kernel<<<(DIM / 128) * TLMAX, 256, 0, stream>>>(
        hbuf, w2, counts, offsets, wgt_buf, tiles, ybuf);

    combine_kernel<<<NTOK, 256, 0, stream>>>((const float4*)ybuf, tok2eq, offsets,
                                             (float4*)out);
    aux_kernel<<<1, 256, 0, stream>>>(probs_buf, out + ((size_t)out_size - 1));
}